// Round 1
// baseline (442.401 us; speedup 1.0000x reference)
//
#include <hip/hip_runtime.h>
#include <hip/hip_bf16.h>
#include <math.h>

// Hierarchy molemap: per-row hierarchical softmax over 65 leaf logits.
// Output 0: leaf_path_probs [N,65]; Output 1: node_probs [N,76], concatenated.
//
// Group boundaries (children of nodes 65..72):
//   (0,7)(7,30)(30,48)(48,53)(53,58)(58,59)(59,62)(62,65)
// Top split: leaves 0..52 -> node 73, leaves 53..64 -> node 74.

#define NLEAF 65
#define NNODE 76

__global__ __launch_bounds__(256) void hier_molemap_kernel(
    const float* __restrict__ x,
    float* __restrict__ out_leaf,   // [N,65]
    float* __restrict__ out_node,   // [N,76]
    int N)
{
    int row = blockIdx.x * blockDim.x + threadIdx.x;
    if (row >= N) return;

    const float* __restrict__ xr = x + (size_t)row * NLEAF;

    // load row into registers
    float v[NLEAF];
#pragma unroll
    for (int i = 0; i < NLEAF; ++i) v[i] = xr[i];

    constexpr int ga[8] = {0, 7, 30, 48, 53, 58, 59, 62};
    constexpr int gb[8] = {7, 30, 48, 53, 58, 59, 62, 65};

    float gsum[8];   // raw sum of logits per group
    float means[8];  // group means (level-2 node logits)

    // per-group softmax (in place: v[] becomes leaf_probs), plus group sums
#pragma unroll
    for (int g = 0; g < 8; ++g) {
        float mx = -INFINITY;
        float sx = 0.0f;
#pragma unroll
        for (int i = ga[g]; i < gb[g]; ++i) {
            mx = fmaxf(mx, v[i]);
            sx += v[i];
        }
        gsum[g] = sx;
        means[g] = sx * (1.0f / (float)(gb[g] - ga[g]));
        float denom = 0.0f;
#pragma unroll
        for (int i = ga[g]; i < gb[g]; ++i) {
            float e = __expf(v[i] - mx);
            v[i] = e;
            denom += e;
        }
        float inv = 1.0f / denom;
#pragma unroll
        for (int i = ga[g]; i < gb[g]; ++i) v[i] *= inv;
    }

    // top-level: m0 = mean(x[0:53]), m1 = mean(x[53:65])
    float m0 = (gsum[0] + gsum[1] + gsum[2] + gsum[3]) * (1.0f / 53.0f);
    float m1 = (gsum[4] + gsum[5] + gsum[6] + gsum[7]) * (1.0f / 12.0f);
    float mt = fmaxf(m0, m1);
    float e0 = __expf(m0 - mt);
    float e1 = __expf(m1 - mt);
    float invt = 1.0f / (e0 + e1);
    float pt0 = e0 * invt;
    float pt1 = e1 * invt;

    // level-2 softmax among siblings: means[0:4] under node 73, means[4:8] under 74
    float p2[8];
    {
        float mxa = fmaxf(fmaxf(means[0], means[1]), fmaxf(means[2], means[3]));
        float sa = 0.0f;
#pragma unroll
        for (int g = 0; g < 4; ++g) { p2[g] = __expf(means[g] - mxa); sa += p2[g]; }
        float inva = 1.0f / sa;
#pragma unroll
        for (int g = 0; g < 4; ++g) p2[g] *= inva;

        float mxb = fmaxf(fmaxf(means[4], means[5]), fmaxf(means[6], means[7]));
        float sb = 0.0f;
#pragma unroll
        for (int g = 4; g < 8; ++g) { p2[g] = __expf(means[g] - mxb); sb += p2[g]; }
        float invb = 1.0f / sb;
#pragma unroll
        for (int g = 4; g < 8; ++g) p2[g] *= invb;
    }

    // node_probs: [leaf_probs(65) | p_lvl2(8) | p_top(2) | 1.0]
    float* __restrict__ nr = out_node + (size_t)row * NNODE;
#pragma unroll
    for (int i = 0; i < NLEAF; ++i) nr[i] = v[i];
#pragma unroll
    for (int g = 0; g < 8; ++g) nr[NLEAF + g] = p2[g];
    nr[73] = pt0;
    nr[74] = pt1;
    nr[75] = 1.0f;

    // leaf_path_probs = leaf_probs * p_lvl2[group(leaf)] * p_top[top(leaf)]
    float* __restrict__ lr = out_leaf + (size_t)row * NLEAF;
#pragma unroll
    for (int g = 0; g < 8; ++g) {
        float f = p2[g] * ((g < 4) ? pt0 : pt1);
#pragma unroll
        for (int i = ga[g]; i < gb[g]; ++i) lr[i] = v[i] * f;
    }
}

extern "C" void kernel_launch(void* const* d_in, const int* in_sizes, int n_in,
                              void* d_out, int out_size, void* d_ws, size_t ws_size,
                              hipStream_t stream) {
    const float* x = (const float*)d_in[0];
    int N = in_sizes[0] / NLEAF;

    float* out_leaf = (float*)d_out;                       // [N,65]
    float* out_node = (float*)d_out + (size_t)N * NLEAF;   // [N,76]

    int block = 256;
    int grid = (N + block - 1) / block;
    hier_molemap_kernel<<<grid, block, 0, stream>>>(x, out_leaf, out_node, N);
}

// Round 2
// 394.420 us; speedup vs baseline: 1.1216x; 1.1216x over previous
//
#include <hip/hip_runtime.h>
#include <hip/hip_bf16.h>
#include <math.h>

// Hierarchy molemap: per-row hierarchical softmax over 65 leaf logits.
// Output 0: leaf_path_probs [N,65]; Output 1: node_probs [N,76], concatenated.
//
// All global traffic is float4-coalesced via LDS staging:
//   in  -> LDS (flat, stride 65 words: 65%32==1 -> conflict-free row reads)
//   leaf out: computed in place in same LDS buffer, streamed out float4
//   node out: LDS stride 77 (77%32==13, odd -> conflict-free), gathered to
//             contiguous float4 (76 = 4*19, float4 never crosses a row)

#define NLEAF 65
#define NNODE 76
#define ROWS  128   // rows per block
#define TPB   128   // threads per block (1 thread = 1 row)
#define NSTRIDE 77  // padded LDS stride for node phase

#define NF   (ROWS * NLEAF)      // 8320 floats per block (leaf-side)
#define NF4  (NF / 4)            // 2080 float4
#define NQ4  (ROWS * (NNODE/4))  // 2432 float4 (node-side), NNODE/4 = 19

__global__ __launch_bounds__(TPB) void hier_molemap_kernel(
    const float* __restrict__ x,
    float* __restrict__ out_leaf,   // [N,65]
    float* __restrict__ out_node,   // [N,76]
    int N)
{
    __shared__ float lds[ROWS * NSTRIDE];   // 128*77*4 = 39424 B

    const int tid  = threadIdx.x;
    const int row0 = blockIdx.x * ROWS;
    if (row0 >= N) return;
    const int R    = min(ROWS, N - row0);
    const bool full = (R == ROWS);

    // ---------- Phase A: coalesced global -> LDS ----------
    if (full) {
        const float4* __restrict__ src4 = (const float4*)(x + (size_t)row0 * NLEAF);
        float4* lds4 = (float4*)lds;
#pragma unroll
        for (int i = 0; i <= NF4 / TPB; ++i) {
            int idx = tid + i * TPB;
            if (idx < NF4) lds4[idx] = src4[idx];
        }
    } else {
        const float* __restrict__ src = x + (size_t)row0 * NLEAF;
        for (int i = tid; i < R * NLEAF; i += TPB) lds[i] = src[i];
    }
    __syncthreads();

    // ---------- Compute (thread t owns row t) ----------
    float v[NLEAF];       // leaf logits -> leaf probs
    float p2[8];
    float pt0 = 0.0f, pt1 = 0.0f;

    constexpr int ga[8] = {0, 7, 30, 48, 53, 58, 59, 62};
    constexpr int gb[8] = {7, 30, 48, 53, 58, 59, 62, 65};

    if (tid < R) {
        const float* __restrict__ r = lds + tid * NLEAF;
#pragma unroll
        for (int i = 0; i < NLEAF; ++i) v[i] = r[i];

        float gsum[8], means[8];
#pragma unroll
        for (int g = 0; g < 8; ++g) {
            float mx = -INFINITY, sx = 0.0f;
#pragma unroll
            for (int i = ga[g]; i < gb[g]; ++i) { mx = fmaxf(mx, v[i]); sx += v[i]; }
            gsum[g]  = sx;
            means[g] = sx * (1.0f / (float)(gb[g] - ga[g]));
            float denom = 0.0f;
#pragma unroll
            for (int i = ga[g]; i < gb[g]; ++i) {
                float e = __expf(v[i] - mx);
                v[i] = e;
                denom += e;
            }
            float inv = 1.0f / denom;
#pragma unroll
            for (int i = ga[g]; i < gb[g]; ++i) v[i] *= inv;
        }

        float m0 = (gsum[0] + gsum[1] + gsum[2] + gsum[3]) * (1.0f / 53.0f);
        float m1 = (gsum[4] + gsum[5] + gsum[6] + gsum[7]) * (1.0f / 12.0f);
        float mt = fmaxf(m0, m1);
        float e0 = __expf(m0 - mt), e1 = __expf(m1 - mt);
        float invt = 1.0f / (e0 + e1);
        pt0 = e0 * invt; pt1 = e1 * invt;

        float mxa = fmaxf(fmaxf(means[0], means[1]), fmaxf(means[2], means[3]));
        float sa = 0.0f;
#pragma unroll
        for (int g = 0; g < 4; ++g) { p2[g] = __expf(means[g] - mxa); sa += p2[g]; }
        float inva = 1.0f / sa;
#pragma unroll
        for (int g = 0; g < 4; ++g) p2[g] *= inva;

        float mxb = fmaxf(fmaxf(means[4], means[5]), fmaxf(means[6], means[7]));
        float sb = 0.0f;
#pragma unroll
        for (int g = 4; g < 8; ++g) { p2[g] = __expf(means[g] - mxb); sb += p2[g]; }
        float invb = 1.0f / sb;
#pragma unroll
        for (int g = 4; g < 8; ++g) p2[g] *= invb;

        // write leaf_path_probs into own LDS row in place (no cross-thread hazard)
        float* __restrict__ w = lds + tid * NLEAF;
#pragma unroll
        for (int g = 0; g < 8; ++g) {
            float f = p2[g] * ((g < 4) ? pt0 : pt1);
#pragma unroll
            for (int i = ga[g]; i < gb[g]; ++i) w[i] = v[i] * f;
        }
    }
    __syncthreads();

    // ---------- Phase C: coalesced LDS -> out_leaf ----------
    if (full) {
        float4* __restrict__ dst4 = (float4*)(out_leaf + (size_t)row0 * NLEAF);
        const float4* lds4 = (const float4*)lds;
#pragma unroll
        for (int i = 0; i <= NF4 / TPB; ++i) {
            int idx = tid + i * TPB;
            if (idx < NF4) dst4[idx] = lds4[idx];
        }
    } else {
        float* __restrict__ dst = out_leaf + (size_t)row0 * NLEAF;
        for (int i = tid; i < R * NLEAF; i += TPB) dst[i] = lds[i];
    }
    __syncthreads();

    // ---------- Phase D: node probs into LDS (stride 77) ----------
    if (tid < R) {
        float* __restrict__ nr = lds + tid * NSTRIDE;
#pragma unroll
        for (int i = 0; i < NLEAF; ++i) nr[i] = v[i];
#pragma unroll
        for (int g = 0; g < 8; ++g) nr[NLEAF + g] = p2[g];
        nr[73] = pt0;
        nr[74] = pt1;
        nr[75] = 1.0f;
    }
    __syncthreads();

    // ---------- Phase E: coalesced LDS -> out_node ----------
    if (full) {
        float4* __restrict__ dst4 = (float4*)(out_node + (size_t)row0 * NNODE);
#pragma unroll
        for (int i = 0; i < NQ4 / TPB; ++i) {   // 2432/128 = 19 exact
            int q = tid + i * TPB;
            int r = q / (NNODE / 4);            // q/19
            int c = q - r * (NNODE / 4);
            const float* s = lds + r * NSTRIDE + c * 4;
            float4 val;
            val.x = s[0]; val.y = s[1]; val.z = s[2]; val.w = s[3];
            dst4[q] = val;
        }
    } else {
        float* __restrict__ dst = out_node + (size_t)row0 * NNODE;
        for (int j = tid; j < R * NNODE; j += TPB) {
            int r = j / NNODE;
            int c = j - r * NNODE;
            dst[j] = lds[r * NSTRIDE + c];
        }
    }
}

extern "C" void kernel_launch(void* const* d_in, const int* in_sizes, int n_in,
                              void* d_out, int out_size, void* d_ws, size_t ws_size,
                              hipStream_t stream) {
    const float* x = (const float*)d_in[0];
    int N = in_sizes[0] / NLEAF;

    float* out_leaf = (float*)d_out;                       // [N,65]
    float* out_node = (float*)d_out + (size_t)N * NLEAF;   // [N,76]

    int grid = (N + ROWS - 1) / ROWS;
    hier_molemap_kernel<<<grid, TPB, 0, stream>>>(x, out_leaf, out_node, N);
}